// Round 5
// baseline (236.588 us; speedup 1.0000x reference)
//
#include <hip/hip_runtime.h>

// GCN 2-layer, N=100k, E=3.2M, IN=2, HID=64, OUT=1 (all float32).
// R5: counting-sort edges by destination bucket (col>>13, 13 buckets) into a
// packed array ((lcol<<17)|row), so hist/s1/s2 read each edge ONCE instead of
// rescanning the full edge list NB times (690MB -> ~90MB of L2/L3 traffic).
// Zero global atomics on the hot path; scatter buckets via LDS, merge dense
// partials per node.

#define NBUCK 13        // ceil(100000/8192)
#define BSH   8192      // nodes per bucket
#define LBITS 13
#define RBITS 17        // row index bits (n < 131072)
#define RMASK ((1 << RBITS) - 1)
#define SORTB 512       // blocks in sort phases
#define TBS   1024
#define TB    1024
#define TN    256

// per-(block,bucket) edge counts via wave ballots (no atomic storms)
__global__ void k_count(const int* __restrict__ col, int* __restrict__ counts, int E) {
    __shared__ int s[NBUCK];
    if (threadIdx.x < NBUCK) s[threadIdx.x] = 0;
    __syncthreads();
    const int lane = threadIdx.x & 63;
    int acc = 0;
    long long e = (long long)blockIdx.x * E / SORTB + threadIdx.x;
    const long long e1 = (long long)(blockIdx.x + 1) * E / SORTB;
    for (;; e += TBS) {
        bool valid = e < e1;
        if (!__any(valid)) break;
        int myb = valid ? (col[e] >> LBITS) : -1;
#pragma unroll
        for (int b = 0; b < NBUCK; ++b) {
            unsigned long long m = __ballot(myb == b);
            if (lane == b) acc += (int)__popcll(m);
        }
    }
    if (lane < NBUCK && acc) atomicAdd(&s[lane], acc);
    __syncthreads();
    if (threadIdx.x < NBUCK) counts[blockIdx.x * NBUCK + threadIdx.x] = s[threadIdx.x];
}

// bucket starts + init cursors (tiny)
__global__ void k_scan(const int* __restrict__ counts, int* __restrict__ cursor,
                       int* __restrict__ bstart) {
    __shared__ int sc[SORTB * NBUCK];
    __shared__ int tot[NBUCK];
    for (int i = threadIdx.x; i < SORTB * NBUCK; i += 256) sc[i] = counts[i];
    __syncthreads();
    if (threadIdx.x < NBUCK) {
        int t = 0;
        for (int j = 0; j < SORTB; ++j) t += sc[j * NBUCK + threadIdx.x];
        tot[threadIdx.x] = t;
    }
    __syncthreads();
    if (threadIdx.x == 0) {
        int a = 0;
        for (int b = 0; b < NBUCK; ++b) { bstart[b] = a; cursor[b] = a; a += tot[b]; }
        bstart[NBUCK] = a;
    }
}

// scatter edges into bucket-sorted packed array; wave-aggregated LDS cursors
__global__ void k_scatter(const int* __restrict__ row, const int* __restrict__ col,
                          const int* __restrict__ counts, int* __restrict__ cursor,
                          int* __restrict__ packed, int E) {
    __shared__ int base[NBUCK];
    if (threadIdx.x < NBUCK) {
        int cnt = counts[blockIdx.x * NBUCK + threadIdx.x];
        base[threadIdx.x] = atomicAdd(&cursor[threadIdx.x], cnt);
    }
    __syncthreads();
    const int lane = threadIdx.x & 63;
    long long e = (long long)blockIdx.x * E / SORTB + threadIdx.x;
    const long long e1 = (long long)(blockIdx.x + 1) * E / SORTB;
    for (;; e += TBS) {
        bool valid = e < e1;
        if (!__any(valid)) break;
        int myb = -1, w = 0;
        if (valid) {
            int c = col[e], r = row[e];
            myb = c >> LBITS;
            w = ((c & (BSH - 1)) << RBITS) | r;
        }
#pragma unroll
        for (int b = 0; b < NBUCK; ++b) {
            unsigned long long m = __ballot(myb == b);
            if (m == 0ull) continue;
            if (myb == b) {
                int lead = __ffsll(m) - 1;
                int pos = 0;
                if (lane == lead) pos = atomicAdd(&base[b], (int)__popcll(m));
                pos = __shfl(pos, lead, 64);
                pos += (int)__popcll(m & ((1ull << lane) - 1ull));
                packed[pos] = w;
            }
        }
    }
}

// in-degree histogram from sorted packed edges (reads each edge once)
__global__ void k_hist(const int* __restrict__ packed, const int* __restrict__ bstart,
                       int* __restrict__ pb, int C) {
    __shared__ int s[BSH];
    const int b = blockIdx.y, j = blockIdx.x;
    for (int i = threadIdx.x; i < BSH; i += TB) s[i] = 0;
    __syncthreads();
    const int s0 = bstart[b];
    const int len = bstart[b + 1] - s0;
    const int e0 = s0 + (int)((long long)len * j / C);
    const int e1 = s0 + (int)((long long)len * (j + 1) / C);
    for (int e = e0 + threadIdx.x; e < e1; e += TB)
        atomicAdd(&s[packed[e] >> RBITS], 1);
    __syncthreads();
    int4* dst = (int4*)(pb + ((size_t)(b * C + j) << LBITS));
    const int4* src = (const int4*)s;
    for (int i = threadIdx.x; i < (BSH >> 2); i += TB) dst[i] = src[i];
}

// merge hist partials -> dinv; y = dinv*x
__global__ void k_post1(const int* __restrict__ pb, const float2* __restrict__ x,
                        float* __restrict__ dinv, float2* __restrict__ y,
                        int n, int C) {
    int i = blockIdx.x * TN + threadIdx.x;
    if (i >= n) return;
    const int b = i >> LBITS, l = i & (BSH - 1);
    int deg = 1;  // self-loop
    const int* p = pb + ((size_t)(b * C) << LBITS) + l;
    for (int j = 0; j < C; ++j) deg += p[(size_t)j << LBITS];
    float d = rsqrtf((float)deg);
    dinv[i] = d;
    float2 xv = x[i];
    y[i] = make_float2(d * xv.x, d * xv.y);
}

// layer-1 scatter from sorted edges: s[lcol] += y[row]
__global__ void k_s1(const int* __restrict__ packed, const int* __restrict__ bstart,
                     const float2* __restrict__ y, float2* __restrict__ pb, int C) {
    __shared__ float2 s[BSH];
    const int b = blockIdx.y, j = blockIdx.x;
    for (int i = threadIdx.x; i < BSH; i += TB) s[i] = make_float2(0.f, 0.f);
    __syncthreads();
    const int s0 = bstart[b];
    const int len = bstart[b + 1] - s0;
    const int e0 = s0 + (int)((long long)len * j / C);
    const int e1 = s0 + (int)((long long)len * (j + 1) / C);
    for (int e = e0 + threadIdx.x; e < e1; e += TB) {
        int w = packed[e];
        float2 v = y[w & RMASK];
        float* sp = (float*)&s[w >> RBITS];
        atomicAdd(sp, v.x);
        atomicAdd(sp + 1, v.y);
    }
    __syncthreads();
    float4* dst = (float4*)(pb + ((size_t)(b * C + j) << LBITS));
    const float4* src = (const float4*)s;
    for (int i = threadIdx.x; i < (BSH >> 1); i += TB) dst[i] = src[i];
}

// merge layer-1 partials + per-node MLP: t = dinv*(relu(a@W1+b1)@W2)
__global__ void k_post2(const float2* __restrict__ pb, const float2* __restrict__ y,
                        const float* __restrict__ dinv,
                        const float* __restrict__ W1, const float* __restrict__ b1,
                        const float* __restrict__ W2,
                        float* __restrict__ t, int n, int C) {
    __shared__ float sW1a[64], sW1b[64], sb1[64], sW2[64];
    if (threadIdx.x < 64) {
        sW1a[threadIdx.x] = W1[threadIdx.x];
        sW1b[threadIdx.x] = W1[64 + threadIdx.x];
        sb1[threadIdx.x]  = b1[threadIdx.x];
        sW2[threadIdx.x]  = W2[threadIdx.x];
    }
    __syncthreads();
    int i = blockIdx.x * TN + threadIdx.x;
    if (i >= n) return;
    const int b = i >> LBITS, l = i & (BSH - 1);
    float gx = 0.f, gy = 0.f;
    const float2* p = pb + ((size_t)(b * C) << LBITS) + l;
    for (int j = 0; j < C; ++j) { float2 v = p[(size_t)j << LBITS]; gx += v.x; gy += v.y; }
    float d = dinv[i];
    float2 yv = y[i];
    float a0 = d * (gx + yv.x);
    float a1 = d * (gy + yv.y);
    float acc = 0.f;
#pragma unroll
    for (int h = 0; h < 64; ++h) {
        float v = fmaf(a0, sW1a[h], fmaf(a1, sW1b[h], sb1[h]));
        acc = fmaf(fmaxf(v, 0.f), sW2[h], acc);
    }
    t[i] = d * acc;
}

// layer-2 scatter from sorted edges: s[lcol] += t[row]
__global__ void k_s2(const int* __restrict__ packed, const int* __restrict__ bstart,
                     const float* __restrict__ t, float* __restrict__ pb, int C) {
    __shared__ float s[BSH];
    const int b = blockIdx.y, j = blockIdx.x;
    for (int i = threadIdx.x; i < BSH; i += TB) s[i] = 0.f;
    __syncthreads();
    const int s0 = bstart[b];
    const int len = bstart[b + 1] - s0;
    const int e0 = s0 + (int)((long long)len * j / C);
    const int e1 = s0 + (int)((long long)len * (j + 1) / C);
    for (int e = e0 + threadIdx.x; e < e1; e += TB) {
        int w = packed[e];
        atomicAdd(&s[w >> RBITS], t[w & RMASK]);
    }
    __syncthreads();
    float4* dst = (float4*)(pb + ((size_t)(b * C + j) << LBITS));
    const float4* src = (const float4*)s;
    for (int i = threadIdx.x; i < (BSH >> 2); i += TB) dst[i] = src[i];
}

// merge layer-2 partials + epilogue
__global__ void k_post3(const float* __restrict__ pb, const float* __restrict__ t,
                        const float* __restrict__ dinv, const float* __restrict__ b2,
                        float* __restrict__ out, int n, int C) {
    int i = blockIdx.x * TN + threadIdx.x;
    if (i >= n) return;
    const int b = i >> LBITS, l = i & (BSH - 1);
    float o = 0.f;
    const float* p = pb + ((size_t)(b * C) << LBITS) + l;
    for (int j = 0; j < C; ++j) o += p[(size_t)j << LBITS];
    out[i] = fmaf(dinv[i], o + t[i], b2[0]);
}

extern "C" void kernel_launch(void* const* d_in, const int* in_sizes, int n_in,
                              void* d_out, int out_size, void* d_ws, size_t ws_size,
                              hipStream_t stream) {
    const float* x  = (const float*)d_in[0];
    const int*   ei = (const int*)d_in[1];
    const float* W1 = (const float*)d_in[2];
    const float* b1 = (const float*)d_in[3];
    const float* W2 = (const float*)d_in[4];
    const float* b2 = (const float*)d_in[5];
    float* out = (float*)d_out;

    const int n = in_sizes[0] / 2;      // 100,000
    const int E = in_sizes[1] / 2;      // 3,200,000
    const int* row = ei;
    const int* col = ei + E;

    // ws: dinv[n] | y[n](f2) | t[n] | bstart[16] | cursor[16] | counts | packed[E] | pb
    char* ws = (char*)d_ws;
    size_t off = 0;
    float*  dinv = (float*)(ws + off);  off += (size_t)n * 4;
    float2* y    = (float2*)(ws + off); off += (size_t)n * 8;
    float*  t    = (float*)(ws + off);  off += (size_t)n * 4;
    int* bstart  = (int*)(ws + off);    off += 16 * 4;
    int* cursor  = (int*)(ws + off);    off += 16 * 4;
    int* counts  = (int*)(ws + off);    off += (size_t)SORTB * NBUCK * 4;
    off = (off + 255) & ~(size_t)255;
    int* packed  = (int*)(ws + off);    off += (size_t)E * 4;
    off = (off + 255) & ~(size_t)255;
    void* pb = (void*)(ws + off);
    size_t pbBytes = ws_size > off ? ws_size - off : 0;

    int C1 = (int)(pbBytes / ((size_t)NBUCK * BSH * 8));  // float2 partials
    int C2 = (int)(pbBytes / ((size_t)NBUCK * BSH * 4));  // int/float partials
    if (C1 > 40) C1 = 40;  if (C1 < 1) C1 = 1;
    if (C2 > 64) C2 = 64;  if (C2 < 1) C2 = 1;

    const int gn = (n + TN - 1) / TN;

    k_count  <<<SORTB, TBS, 0, stream>>>(col, counts, E);
    k_scan   <<<1, 256, 0, stream>>>(counts, cursor, bstart);
    k_scatter<<<SORTB, TBS, 0, stream>>>(row, col, counts, cursor, packed, E);
    k_hist   <<<dim3(C2, NBUCK), TB, 0, stream>>>(packed, bstart, (int*)pb, C2);
    k_post1  <<<gn, TN, 0, stream>>>((const int*)pb, (const float2*)x, dinv, y, n, C2);
    k_s1     <<<dim3(C1, NBUCK), TB, 0, stream>>>(packed, bstart, y, (float2*)pb, C1);
    k_post2  <<<gn, TN, 0, stream>>>((const float2*)pb, y, dinv, W1, b1, W2, t, n, C1);
    k_s2     <<<dim3(C2, NBUCK), TB, 0, stream>>>(packed, bstart, t, (float*)pb, C2);
    k_post3  <<<gn, TN, 0, stream>>>((const float*)pb, t, dinv, b2, out, n, C2);
}

// Round 6
// 198.759 us; speedup vs baseline: 1.1903x; 1.1903x over previous
//
#include <hip/hip_runtime.h>

// GCN 2-layer, N=100k, E=3.2M, IN=2, HID=64, OUT=1 (all float32).
// R6: one-kernel staged counting sort by dest bucket (col>>13, 13 buckets,
// fixed CAP regions). Blocks stage edges in LDS per-bucket buffers, reserve
// ranges with 13 global atomics/block, copy out coalesced. Replaces R5's
// count+scan+scatter trio (~110us: serial scan, ballot ladders, scattered
// 4B writes). Scans (hist/s1/s2) then read each edge exactly once.

#define NBUCK 13        // ceil(100000/8192)
#define BSH   8192      // nodes per bucket
#define LBITS 13
#define RBITS 17        // row bits (n < 131072)
#define RMASK ((1 << RBITS) - 1)
#define CAP   300000    // global per-bucket capacity (mean 262k, ~77 sigma)
#define SB    1024      // sort blocks
#define TBS   512
#define SCAP  768       // per-block per-bucket staging (mean 256, ~33 sigma)
#define TB    1024
#define TN    256

__global__ void k_init0(int* __restrict__ gcur) {
    if (threadIdx.x < NBUCK) gcur[threadIdx.x] = threadIdx.x * CAP;
}

// staged counting sort: packed[b-region] gets ((lcol<<RBITS)|row), grouped by b
__global__ void k_sort(const int* __restrict__ row, const int* __restrict__ col,
                       int* __restrict__ gcur, int* __restrict__ packed, int E) {
    __shared__ int fill[NBUCK];
    __shared__ int gb[NBUCK];
    __shared__ int stage[NBUCK * SCAP];   // 39KB
    if (threadIdx.x < NBUCK) fill[threadIdx.x] = 0;
    __syncthreads();
    const int e0 = (int)((long long)blockIdx.x * E / SB);
    const int e1 = (int)((long long)(blockIdx.x + 1) * E / SB);
    for (int e = e0 + threadIdx.x; e < e1; e += TBS) {
        int c = col[e];
        int b = c >> LBITS;
        int w = ((c & (BSH - 1)) << RBITS) | row[e];
        int p = atomicAdd(&fill[b], 1);
        if (p < SCAP) stage[b * SCAP + p] = w;
        else { int gp = atomicAdd(&gcur[b], 1); packed[gp] = w; }  // rare fallback
    }
    __syncthreads();
    if (threadIdx.x < NBUCK) {
        int cnt = min(fill[threadIdx.x], SCAP);
        gb[threadIdx.x] = atomicAdd(&gcur[threadIdx.x], cnt);
    }
    __syncthreads();
    for (int b = 0; b < NBUCK; ++b) {         // coalesced copy-out
        int cnt = min(fill[b], SCAP);
        for (int i = threadIdx.x; i < cnt; i += TBS)
            packed[gb[b] + i] = stage[b * SCAP + i];
    }
}

// in-degree histogram from bucket-sorted packed edges
__global__ void k_hist(const int* __restrict__ packed, const int* __restrict__ gcur,
                       int* __restrict__ pb, int C) {
    __shared__ int s[BSH];
    const int b = blockIdx.y, j = blockIdx.x;
    for (int i = threadIdx.x; i < BSH; i += TB) s[i] = 0;
    __syncthreads();
    const int base = b * CAP;
    const int len = gcur[b] - base;
    const int a0 = base + (int)((long long)len * j / C);
    const int a1 = base + (int)((long long)len * (j + 1) / C);
    for (int e = a0 + threadIdx.x; e < a1; e += TB)
        atomicAdd(&s[packed[e] >> RBITS], 1);
    __syncthreads();
    int4* dst = (int4*)(pb + ((size_t)(b * C + j) << LBITS));
    const int4* src = (const int4*)s;
    for (int i = threadIdx.x; i < (BSH >> 2); i += TB) dst[i] = src[i];
}

// merge hist partials -> dinv; y = dinv*x
__global__ void k_post1(const int* __restrict__ pb, const float2* __restrict__ x,
                        float* __restrict__ dinv, float2* __restrict__ y,
                        int n, int C) {
    int i = blockIdx.x * TN + threadIdx.x;
    if (i >= n) return;
    const int b = i >> LBITS, l = i & (BSH - 1);
    int deg = 1;  // self-loop
    const int* p = pb + ((size_t)(b * C) << LBITS) + l;
    for (int j = 0; j < C; ++j) deg += p[(size_t)j << LBITS];
    float d = rsqrtf((float)deg);
    dinv[i] = d;
    float2 xv = x[i];
    y[i] = make_float2(d * xv.x, d * xv.y);
}

// layer-1 scatter: s[lcol] += y[row]
__global__ void k_s1(const int* __restrict__ packed, const int* __restrict__ gcur,
                     const float2* __restrict__ y, float2* __restrict__ pb, int C) {
    __shared__ float2 s[BSH];
    const int b = blockIdx.y, j = blockIdx.x;
    for (int i = threadIdx.x; i < BSH; i += TB) s[i] = make_float2(0.f, 0.f);
    __syncthreads();
    const int base = b * CAP;
    const int len = gcur[b] - base;
    const int a0 = base + (int)((long long)len * j / C);
    const int a1 = base + (int)((long long)len * (j + 1) / C);
    for (int e = a0 + threadIdx.x; e < a1; e += TB) {
        int w = packed[e];
        float2 v = y[w & RMASK];
        float* sp = (float*)&s[w >> RBITS];
        atomicAdd(sp, v.x);
        atomicAdd(sp + 1, v.y);
    }
    __syncthreads();
    float4* dst = (float4*)(pb + ((size_t)(b * C + j) << LBITS));
    const float4* src = (const float4*)s;
    for (int i = threadIdx.x; i < (BSH >> 1); i += TB) dst[i] = src[i];
}

// merge layer-1 partials + per-node MLP: t = dinv*(relu(a@W1+b1)@W2)
__global__ void k_post2(const float2* __restrict__ pb, const float2* __restrict__ y,
                        const float* __restrict__ dinv,
                        const float* __restrict__ W1, const float* __restrict__ b1,
                        const float* __restrict__ W2,
                        float* __restrict__ t, int n, int C) {
    __shared__ float sW1a[64], sW1b[64], sb1[64], sW2[64];
    if (threadIdx.x < 64) {
        sW1a[threadIdx.x] = W1[threadIdx.x];
        sW1b[threadIdx.x] = W1[64 + threadIdx.x];
        sb1[threadIdx.x]  = b1[threadIdx.x];
        sW2[threadIdx.x]  = W2[threadIdx.x];
    }
    __syncthreads();
    int i = blockIdx.x * TN + threadIdx.x;
    if (i >= n) return;
    const int b = i >> LBITS, l = i & (BSH - 1);
    float gx = 0.f, gy = 0.f;
    const float2* p = pb + ((size_t)(b * C) << LBITS) + l;
    for (int j = 0; j < C; ++j) { float2 v = p[(size_t)j << LBITS]; gx += v.x; gy += v.y; }
    float d = dinv[i];
    float2 yv = y[i];
    float a0 = d * (gx + yv.x);
    float a1 = d * (gy + yv.y);
    float acc = 0.f;
#pragma unroll
    for (int h = 0; h < 64; ++h) {
        float v = fmaf(a0, sW1a[h], fmaf(a1, sW1b[h], sb1[h]));
        acc = fmaf(fmaxf(v, 0.f), sW2[h], acc);
    }
    t[i] = d * acc;
}

// layer-2 scatter: s[lcol] += t[row]
__global__ void k_s2(const int* __restrict__ packed, const int* __restrict__ gcur,
                     const float* __restrict__ t, float* __restrict__ pb, int C) {
    __shared__ float s[BSH];
    const int b = blockIdx.y, j = blockIdx.x;
    for (int i = threadIdx.x; i < BSH; i += TB) s[i] = 0.f;
    __syncthreads();
    const int base = b * CAP;
    const int len = gcur[b] - base;
    const int a0 = base + (int)((long long)len * j / C);
    const int a1 = base + (int)((long long)len * (j + 1) / C);
    for (int e = a0 + threadIdx.x; e < a1; e += TB) {
        int w = packed[e];
        atomicAdd(&s[w >> RBITS], t[w & RMASK]);
    }
    __syncthreads();
    float4* dst = (float4*)(pb + ((size_t)(b * C + j) << LBITS));
    const float4* src = (const float4*)s;
    for (int i = threadIdx.x; i < (BSH >> 2); i += TB) dst[i] = src[i];
}

// merge layer-2 partials + epilogue
__global__ void k_post3(const float* __restrict__ pb, const float* __restrict__ t,
                        const float* __restrict__ dinv, const float* __restrict__ b2,
                        float* __restrict__ out, int n, int C) {
    int i = blockIdx.x * TN + threadIdx.x;
    if (i >= n) return;
    const int b = i >> LBITS, l = i & (BSH - 1);
    float o = 0.f;
    const float* p = pb + ((size_t)(b * C) << LBITS) + l;
    for (int j = 0; j < C; ++j) o += p[(size_t)j << LBITS];
    out[i] = fmaf(dinv[i], o + t[i], b2[0]);
}

extern "C" void kernel_launch(void* const* d_in, const int* in_sizes, int n_in,
                              void* d_out, int out_size, void* d_ws, size_t ws_size,
                              hipStream_t stream) {
    const float* x  = (const float*)d_in[0];
    const int*   ei = (const int*)d_in[1];
    const float* W1 = (const float*)d_in[2];
    const float* b1 = (const float*)d_in[3];
    const float* W2 = (const float*)d_in[4];
    const float* b2 = (const float*)d_in[5];
    float* out = (float*)d_out;

    const int n = in_sizes[0] / 2;      // 100,000
    const int E = in_sizes[1] / 2;      // 3,200,000
    const int* row = ei;
    const int* col = ei + E;

    // ws: dinv[n] | y[n](f2) | t[n] | gcur[16] | packed[13*CAP] | pb
    char* ws = (char*)d_ws;
    size_t off = 0;
    float*  dinv = (float*)(ws + off);  off += (size_t)n * 4;
    float2* y    = (float2*)(ws + off); off += (size_t)n * 8;
    float*  t    = (float*)(ws + off);  off += (size_t)n * 4;
    off = (off + 255) & ~(size_t)255;
    int* gcur    = (int*)(ws + off);    off += 16 * 4;
    off = (off + 255) & ~(size_t)255;
    int* packed  = (int*)(ws + off);    off += (size_t)NBUCK * CAP * 4;
    off = (off + 255) & ~(size_t)255;
    void* pb = (void*)(ws + off);
    size_t pbBytes = ws_size > off ? ws_size - off : 0;

    int C1 = (int)(pbBytes / ((size_t)NBUCK * BSH * 8));  // float2 partials
    int C2 = (int)(pbBytes / ((size_t)NBUCK * BSH * 4));  // int/float partials
    if (C1 > 40) C1 = 40;  if (C1 < 1) C1 = 1;   // 520 blocks, 2/CU residency
    if (C2 > 40) C2 = 40;  if (C2 < 1) C2 = 1;

    const int gn = (n + TN - 1) / TN;

    k_init0<<<1, 64, 0, stream>>>(gcur);
    k_sort <<<SB, TBS, 0, stream>>>(row, col, gcur, packed, E);
    k_hist <<<dim3(C2, NBUCK), TB, 0, stream>>>(packed, gcur, (int*)pb, C2);
    k_post1<<<gn, TN, 0, stream>>>((const int*)pb, (const float2*)x, dinv, y, n, C2);
    k_s1   <<<dim3(C1, NBUCK), TB, 0, stream>>>(packed, gcur, y, (float2*)pb, C1);
    k_post2<<<gn, TN, 0, stream>>>((const float2*)pb, y, dinv, W1, b1, W2, t, n, C1);
    k_s2   <<<dim3(C2, NBUCK), TB, 0, stream>>>(packed, gcur, t, (float*)pb, C2);
    k_post3<<<gn, TN, 0, stream>>>((const float*)pb, t, dinv, b2, out, n, C2);
}